// Round 17
// baseline (369.683 us; speedup 1.0000x reference)
//
#include <hip/hip_runtime.h>
#include <math.h>

#define NRW 131072
#define W   128
#define K   1024
#define C   4
#define BN  64
#define NT  256

typedef _Float16 f16;
typedef _Float16 f16x8 __attribute__((ext_vector_type(8)));
typedef float    f32x4 __attribute__((ext_vector_type(4)));
typedef unsigned long long u64;

__device__ __forceinline__ float fmulr(float a, float b){ return __fmul_rn(a,b); }
__device__ __forceinline__ float faddr(float a, float b){ return __fadd_rn(a,b); }
__device__ __forceinline__ float fsubr(float a, float b){ return __fsub_rn(a,b); }
__device__ __forceinline__ unsigned umin32(unsigned a, unsigned b){ return a < b ? a : b; }
__device__ __forceinline__ unsigned umax32(unsigned a, unsigned b){ return a > b ? a : b; }

// XLA:CPU reduce bits: acc = fl(acc + fl(v*v)), ascending, init 0
__device__ float seq_sumsq_glb(const float* __restrict__ p){
    float a = 0.f;
    for (int w = 0; w < W; ++w){ const float v = p[w]; a = faddr(a, fmulr(v, v)); }
    return a;
}

__global__ __launch_bounds__(256) void c2_kernel(const float* __restrict__ CB,
                                                 float* __restrict__ c2g){
    const int kg = blockIdx.x * 256 + threadIdx.x;
    if (kg < C * K) c2g[kg] = seq_sumsq_glb(CB + (size_t)kg * W);
}

// f16 hi-only, fragment-major B layout for mfma_f32_16x16x32_f16 (verified R9-R15):
// off = (((s*64 + (k>>4))*4 + q)*64 + ((w8&3)*16 + (k&15)))*8, q = w>>5, w8 = w>>3
__global__ __launch_bounds__(256) void split_kernel(const float* __restrict__ CB,
                                                    f16* __restrict__ Bh){
    const int g  = blockIdx.x * 256 + threadIdx.x;     // 65536 total
    const int s  = g >> 14, k = (g >> 4) & 1023, w8 = g & 15;
    const float* src = CB + ((size_t)(s * K + k)) * W + w8 * 8;
    const size_t off = ((((size_t)(s * 64 + (k >> 4)) * 4 + (w8 >> 2)) * 64)
                        + ((w8 & 3) * 16 + (k & 15))) * 8;
    f16x8 hv;
    #pragma unroll
    for (int j = 0; j < 8; ++j) hv[j] = (f16)src[j];
    *(f16x8*)(Bh + off) = hv;
}

// 6-op insert: score = fl(c2b - 2*acc), POSITIVE (c2b pre-biased +512) -> bits are
// integer-ordered; 27 value bits | 5-bit kbi (kbi in [0,32); col/kh implicit).
#define PACK_INS6(ACCV, C2B, KBIV, S1, S2)                                              \
    {                                                                                   \
        const float sv = fmaf(-2.f, (ACCV), (C2B));                                     \
        const unsigned uu = (__float_as_uint(sv) & 0xFFFFFFE0u) | (KBIV);               \
        const unsigned mn = umin32((S1), uu);                                           \
        (S2) = umin32((S2), umax32((S1), uu));                                          \
        (S1) = mn;                                                                      \
    }

#define INS4_64(VAL, C0, C1, C2, C3)                                                    \
    {                                                                                   \
        const u64 v_ = (VAL);                                                           \
        if (v_ < (C3)){                                                                 \
            if (v_ < (C2)){ (C3) = (C2);                                                \
                if (v_ < (C1)){ (C2) = (C1);                                            \
                    if (v_ < (C0)){ (C1) = (C0); (C0) = v_; } else (C1) = v_;           \
                } else (C2) = v_;                                                       \
            } else (C3) = v_;                                                           \
        }                                                                               \
    }

__global__ __launch_bounds__(NT, 3) void rq17_kernel(
    const float* __restrict__ X, const float* __restrict__ CB,
    const float* __restrict__ c2g, const f16* __restrict__ BhG,
    float* __restrict__ out)
{
    __shared__ float Rt[BN][W + 4];      // 33.8 KB, stride 132
    __shared__ float c2l[K];             // 4 KB, biased +512
    __shared__ u64   mslot[BN * 5];      // 2.5 KB: [row][kh*2+i], stride 5
    __shared__ int   cand[BN][4];
    __shared__ float dve[BN][4];
    __shared__ int   widx[BN];

    const int tid = threadIdx.x;
    const int wv  = tid >> 6;
    const int rh  = wv >> 1;       // row half: rows [rh*32, rh*32+32)
    const int kh  = wv & 1;        // k half: kb in [kh*32, kh*32+32)
    const int ln  = tid & 63;
    const int col = ln & 15;
    const int n0  = blockIdx.x * BN;

    // ---- initial residual = X ----
    for (int e = tid; e < BN * 32; e += NT){
        const int row = e >> 5, q = e & 31;
        const float4 v = *(const float4*)(X + (size_t)(n0 + row) * W + q * 4);
        *(float4*)(&Rt[row][q * 4]) = v;
    }

    for (int st = 0; st < C; ++st){
        const float*  cb  = CB + (size_t)st * K * W;
        const float4* cb4 = (const float4*)cb;
        const f16*    BhS = BhG + (size_t)st * 131072;

        __syncthreads();   // Rt stable (fill or update)

        // biased c2 for the scan (exact phase uses unbiased c2g)
        for (int kk = tid; kk < K; kk += NT) c2l[kk] = c2g[st * K + kk] + 512.0f;
        __syncthreads();

        // ---- A fragments: this wave's 32 rows, f32->f16, PINNED in registers ----
        f16x8 a[2][4];
        #pragma unroll
        for (int rbl = 0; rbl < 2; ++rbl){
            #pragma unroll
            for (int q = 0; q < 4; ++q){
                const int row = rh * 32 + rbl * 16 + (ln & 15);
                const int w0  = q * 32 + ((ln >> 4) << 3);
                const float* rp = &Rt[row][w0];
                f16x8 h;
                #pragma unroll
                for (int j = 0; j < 8; ++j) h[j] = (f16)rp[j];
                a[rbl][q] = h;
                asm volatile("" : "+v"(a[rbl][q]));   // pin: forbid LDS rematerialization
            }
        }

        unsigned s1[2][4], s2[2][4];
        #pragma unroll
        for (int i = 0; i < 2; ++i)
            #pragma unroll
            for (int j = 0; j < 4; ++j){ s1[i][j] = 0xFFFFFFFFu; s2[i][j] = 0xFFFFFFFFu; }

        // ---- MFMA scan: 32 kb of this k-half, 27|5-packed top-2 per (rbl,rg) chain ----
        #pragma unroll 2
        for (int kbi = 0; kbi < 32; ++kbi){
            const int kb = kh * 32 + kbi;
            f16x8 bh0 = *(const f16x8*)(BhS + ((size_t)(kb * 4 + 0) * 64 + ln) * 8);
            f16x8 bh1 = *(const f16x8*)(BhS + ((size_t)(kb * 4 + 1) * 64 + ln) * 8);
            f16x8 bh2 = *(const f16x8*)(BhS + ((size_t)(kb * 4 + 2) * 64 + ln) * 8);
            f16x8 bh3 = *(const f16x8*)(BhS + ((size_t)(kb * 4 + 3) * 64 + ln) * 8);
            const float    c2b  = c2l[(kb << 4) + col];
            const unsigned kbiv = (unsigned)kbi;

            #pragma unroll
            for (int rbl = 0; rbl < 2; ++rbl){
                f32x4 acc = {0.f, 0.f, 0.f, 0.f};
                acc = __builtin_amdgcn_mfma_f32_16x16x32_f16(a[rbl][0], bh0, acc, 0, 0, 0);
                acc = __builtin_amdgcn_mfma_f32_16x16x32_f16(a[rbl][1], bh1, acc, 0, 0, 0);
                acc = __builtin_amdgcn_mfma_f32_16x16x32_f16(a[rbl][2], bh2, acc, 0, 0, 0);
                acc = __builtin_amdgcn_mfma_f32_16x16x32_f16(a[rbl][3], bh3, acc, 0, 0, 0);
                PACK_INS6(acc[0], c2b, kbiv, s1[rbl][0], s2[rbl][0]);
                PACK_INS6(acc[1], c2b, kbiv, s1[rbl][1], s2[rbl][1]);
                PACK_INS6(acc[2], c2b, kbiv, s1[rbl][2], s2[rbl][2]);
                PACK_INS6(acc[3], c2b, kbiv, s1[rbl][3], s2[rbl][3]);
            }
        }

        // ---- flush: unpack to full-precision u64 (score27<<32 | k10), shfl top-2 merge ----
        const unsigned kbase = (unsigned)((kh * 32) << 4) + (unsigned)col;
        #pragma unroll
        for (int rbl = 0; rbl < 2; ++rbl){
            #pragma unroll
            for (int rg = 0; rg < 4; ++rg){
                const unsigned v1 = s1[rbl][rg], v2 = s2[rbl][rg];
                u64 a1 = ((u64)(v1 & 0xFFFFFFE0u) << 32) | (u64)(((v1 & 31u) << 4) + kbase);
                u64 a2 = ((u64)(v2 & 0xFFFFFFE0u) << 32) | (u64)(((v2 & 31u) << 4) + kbase);
                #pragma unroll
                for (int m = 1; m <= 8; m <<= 1){
                    const u64 o1 = (u64)__shfl_xor((long long)a1, m, 16);
                    const u64 o2 = (u64)__shfl_xor((long long)a2, m, 16);
                    const u64 t  = a1 > o1 ? a1 : o1;
                    a1 = a1 < o1 ? a1 : o1;
                    const u64 u2 = a2 < o2 ? a2 : o2;
                    a2 = t < u2 ? t : u2;
                }
                if (col == 0){
                    const int row = rh * 32 + rbl * 16 + ((ln >> 4) << 2) + rg;
                    mslot[row * 5 + kh * 2 + 0] = a1;
                    mslot[row * 5 + kh * 2 + 1] = a2;
                }
            }
        }
        __syncthreads();   // all wave top-2 written

        // ---- merge: top-4 per row from 2 k-halves x top-2 (u64 lexicographic) ----
        if (tid < BN){
            u64 c0 = ~0ull, c1 = ~0ull, c2m = ~0ull, c3 = ~0ull;
            #pragma unroll
            for (int i = 0; i < 4; ++i){
                const u64 v = mslot[tid * 5 + i];
                INS4_64(v, c0, c1, c2m, c3);
            }
            cand[tid][0] = (int)(c0 & 1023u);
            cand[tid][1] = (int)(c1 & 1023u);
            cand[tid][2] = (int)(c2m & 1023u);
            cand[tid][3] = (int)(c3 & 1023u);
        }
        __syncthreads();

        // ---- exact XLA-bits re-eval of 4 candidates (256 threads = 64 rows x 4) ----
        {
            const int row = tid >> 2, cd = tid & 3;
            const int k = cand[row][cd];
            const float* cw = cb + (size_t)k * W;
            float r2 = 0.f, dot = 0.f;
            for (int w = 0; w < W; ++w){
                const float rv = Rt[row][w];
                r2  = faddr(r2, fmulr(rv, rv));
                dot = __fmaf_rn(rv, cw[w], dot);
            }
            dve[row][cd] = faddr(fsubr(r2, faddr(dot, dot)), c2g[st * K + k]);
        }
        __syncthreads();

        // ---- decide: lexicographic (d2, k) min among 4 = XLA first-min ----
        if (tid < BN){
            float bd = dve[tid][0]; int bk = cand[tid][0];
            #pragma unroll
            for (int j = 1; j < 4; ++j){
                const float d = dve[tid][j]; const int k = cand[tid][j];
                if (d < bd || (d == bd && k < bk)){ bd = d; bk = k; }
            }
            widx[tid] = bk;
            out[(size_t)st * NRW + (n0 + tid)] = (float)bk;
            out[(size_t)C * NRW + (size_t)(n0 + tid) * C + st] = __fsqrt_rn(fmaxf(bd, 0.f));
        }
        __syncthreads();

        // ---- residual -= cb[idx], elementwise f32 (bit-exact) ----
        if (st < C - 1){
            for (int e = tid; e < BN * 32; e += NT){
                const int row = e >> 5, q = e & 31;
                const float4 v = cb4[(size_t)widx[row] * 32 + q];
                float* rp = &Rt[row][q * 4];
                rp[0] = fsubr(rp[0], v.x);
                rp[1] = fsubr(rp[1], v.y);
                rp[2] = fsubr(rp[2], v.z);
                rp[3] = fsubr(rp[3], v.w);
            }
        }
    }
}

extern "C" void kernel_launch(void* const* d_in, const int* in_sizes, int n_in,
                              void* d_out, int out_size, void* d_ws, size_t ws_size,
                              hipStream_t stream) {
    const float* X  = (const float*)d_in[0];
    const float* CB = (const float*)d_in[1];
    float* out = (float*)d_out;

    float* c2g = (float*)d_ws;                    // 16 KB
    f16*   Bh  = (f16*)((char*)d_ws + 16384);     // 1 MB

    c2_kernel<<<dim3((C * K + 255) / 256), 256, 0, stream>>>(CB, c2g);
    split_kernel<<<dim3(C * K * 16 / 256), 256, 0, stream>>>(CB, Bh);
    rq17_kernel<<<dim3(NRW / BN), NT, 0, stream>>>(X, CB, c2g, Bh, out);
}

// Round 18
// 358.475 us; speedup vs baseline: 1.0313x; 1.0313x over previous
//
#include <hip/hip_runtime.h>
#include <math.h>

#define NRW 131072
#define W   128
#define K   1024
#define C   4
#define BN  64
#define NT  256

typedef _Float16 f16;
typedef _Float16 f16x8 __attribute__((ext_vector_type(8)));
typedef float    f32x4 __attribute__((ext_vector_type(4)));
typedef unsigned long long u64;

__device__ __forceinline__ float fmulr(float a, float b){ return __fmul_rn(a,b); }
__device__ __forceinline__ float faddr(float a, float b){ return __fadd_rn(a,b); }
__device__ __forceinline__ float fsubr(float a, float b){ return __fsub_rn(a,b); }
__device__ __forceinline__ unsigned umin32(unsigned a, unsigned b){ return a < b ? a : b; }
__device__ __forceinline__ unsigned umax32(unsigned a, unsigned b){ return a > b ? a : b; }

// XLA:CPU reduce bits: acc = fl(acc + fl(v*v)), ascending, init 0
__device__ float seq_sumsq_glb(const float* __restrict__ p){
    float a = 0.f;
    for (int w = 0; w < W; ++w){ const float v = p[w]; a = faddr(a, fmulr(v, v)); }
    return a;
}

__global__ __launch_bounds__(256) void c2_kernel(const float* __restrict__ CB,
                                                 float* __restrict__ c2g){
    const int kg = blockIdx.x * 256 + threadIdx.x;
    if (kg < C * K) c2g[kg] = seq_sumsq_glb(CB + (size_t)kg * W);
}

// f16 hi-only, fragment-major B layout for mfma_f32_16x16x32_f16 (verified R9-R17):
// off = (((s*64 + (k>>4))*4 + q)*64 + ((w8&3)*16 + (k&15)))*8, q = w>>5, w8 = w>>3
__global__ __launch_bounds__(256) void split_kernel(const float* __restrict__ CB,
                                                    f16* __restrict__ Bh){
    const int g  = blockIdx.x * 256 + threadIdx.x;     // 65536 total
    const int s  = g >> 14, k = (g >> 4) & 1023, w8 = g & 15;
    const float* src = CB + ((size_t)(s * K + k)) * W + w8 * 8;
    const size_t off = ((((size_t)(s * 64 + (k >> 4)) * 4 + (w8 >> 2)) * 64)
                        + ((w8 & 3) * 16 + (k & 15))) * 8;
    f16x8 hv;
    #pragma unroll
    for (int j = 0; j < 8; ++j) hv[j] = (f16)src[j];
    *(f16x8*)(Bh + off) = hv;
}

// 6-op insert: score = fl(c2b - 2*acc), POSITIVE (c2b pre-biased +512) -> bits are
// integer-ordered; 28 value bits | 4-bit kbi (kbi in [0,16); col/wv implicit).
#define PACK_INS6(ACCV, C2B, KBIV, S1, S2)                                              \
    {                                                                                   \
        const float sv = fmaf(-2.f, (ACCV), (C2B));                                     \
        const unsigned uu = (__float_as_uint(sv) & 0xFFFFFFF0u) | (KBIV);               \
        const unsigned mn = umin32((S1), uu);                                           \
        (S2) = umin32((S2), umax32((S1), uu));                                          \
        (S1) = mn;                                                                      \
    }

#define INS4_64(VAL, C0, C1, C2, C3)                                                    \
    {                                                                                   \
        const u64 v_ = (VAL);                                                           \
        if (v_ < (C3)){                                                                 \
            if (v_ < (C2)){ (C3) = (C2);                                                \
                if (v_ < (C1)){ (C2) = (C1);                                            \
                    if (v_ < (C0)){ (C1) = (C0); (C0) = v_; } else (C1) = v_;           \
                } else (C2) = v_;                                                       \
            } else (C3) = v_;                                                           \
        }                                                                               \
    }

__global__ __launch_bounds__(NT, 3) void rq18_kernel(
    const float* __restrict__ X, const float* __restrict__ CB,
    const float* __restrict__ c2g, const f16* __restrict__ BhG,
    float* __restrict__ out)
{
    __shared__ float Rt[BN][W + 4];      // 33.8 KB, stride 132
    __shared__ u64   mslot[BN * 9];      // 4.6 KB: [row][wv*2+i], stride 9
    __shared__ int   cand[BN][4];
    __shared__ float dve[BN][4];
    __shared__ int   widx[BN];

    const int tid = threadIdx.x;
    const int wv  = tid >> 6;      // 0..3: owns kb in [wv*16, wv*16+16)
    const int ln  = tid & 63;
    const int col = ln & 15;
    const int n0  = blockIdx.x * BN;

    // ---- initial residual = X ----
    for (int e = tid; e < BN * 32; e += NT){
        const int row = e >> 5, q = e & 31;
        const float4 v = *(const float4*)(X + (size_t)(n0 + row) * W + q * 4);
        *(float4*)(&Rt[row][q * 4]) = v;
    }

    for (int st = 0; st < C; ++st){
        const float*  cb  = CB + (size_t)st * K * W;
        const float4* cb4 = (const float4*)cb;
        const f16*    BhS = BhG + (size_t)st * 131072;

        __syncthreads();   // Rt stable (fill or update)

        // ---- biased c2 for this wave's 16 kb, in registers (L2 reads, once/stage) ----
        float c2reg[16];
        #pragma unroll
        for (int kbi = 0; kbi < 16; ++kbi)
            c2reg[kbi] = c2g[st * K + (((wv * 16 + kbi) << 4) + col)] + 512.0f;

        // ---- A fragments: all 64 rows, f32->f16, PINNED in registers ----
        f16x8 a[4][4];
        #pragma unroll
        for (int rbl = 0; rbl < 4; ++rbl){
            #pragma unroll
            for (int q = 0; q < 4; ++q){
                const int row = rbl * 16 + (ln & 15);
                const int w0  = q * 32 + ((ln >> 4) << 3);
                const float* rp = &Rt[row][w0];
                f16x8 h;
                #pragma unroll
                for (int j = 0; j < 8; ++j) h[j] = (f16)rp[j];
                a[rbl][q] = h;
                asm volatile("" : "+v"(a[rbl][q]));   // pin: forbid LDS rematerialization
            }
        }

        unsigned s1[4][4], s2[4][4];
        #pragma unroll
        for (int i = 0; i < 4; ++i)
            #pragma unroll
            for (int j = 0; j < 4; ++j){ s1[i][j] = 0xFFFFFFFFu; s2[i][j] = 0xFFFFFFFFu; }

        // ---- MFMA scan: 16 kb of this wave; 16 MFMA + 16 packs per 4 B-loads ----
        #pragma unroll 2
        for (int kbi = 0; kbi < 16; ++kbi){
            const int kb = wv * 16 + kbi;
            f16x8 bh0 = *(const f16x8*)(BhS + ((size_t)(kb * 4 + 0) * 64 + ln) * 8);
            f16x8 bh1 = *(const f16x8*)(BhS + ((size_t)(kb * 4 + 1) * 64 + ln) * 8);
            f16x8 bh2 = *(const f16x8*)(BhS + ((size_t)(kb * 4 + 2) * 64 + ln) * 8);
            f16x8 bh3 = *(const f16x8*)(BhS + ((size_t)(kb * 4 + 3) * 64 + ln) * 8);
            const float    c2b  = c2reg[kbi];
            const unsigned kbiv = (unsigned)kbi;

            #pragma unroll
            for (int rbl = 0; rbl < 4; ++rbl){
                f32x4 acc = {0.f, 0.f, 0.f, 0.f};
                acc = __builtin_amdgcn_mfma_f32_16x16x32_f16(a[rbl][0], bh0, acc, 0, 0, 0);
                acc = __builtin_amdgcn_mfma_f32_16x16x32_f16(a[rbl][1], bh1, acc, 0, 0, 0);
                acc = __builtin_amdgcn_mfma_f32_16x16x32_f16(a[rbl][2], bh2, acc, 0, 0, 0);
                acc = __builtin_amdgcn_mfma_f32_16x16x32_f16(a[rbl][3], bh3, acc, 0, 0, 0);
                PACK_INS6(acc[0], c2b, kbiv, s1[rbl][0], s2[rbl][0]);
                PACK_INS6(acc[1], c2b, kbiv, s1[rbl][1], s2[rbl][1]);
                PACK_INS6(acc[2], c2b, kbiv, s1[rbl][2], s2[rbl][2]);
                PACK_INS6(acc[3], c2b, kbiv, s1[rbl][3], s2[rbl][3]);
            }
        }

        // ---- flush: unpack to u64 (score28<<32 | k10), width-16 shfl top-2 merge ----
        const unsigned kbase = ((unsigned)wv << 8) + (unsigned)col;   // (wv*16+kbi)<<4 + col
        #pragma unroll
        for (int rbl = 0; rbl < 4; ++rbl){
            #pragma unroll
            for (int rg = 0; rg < 4; ++rg){
                const unsigned v1 = s1[rbl][rg], v2 = s2[rbl][rg];
                u64 a1 = ((u64)(v1 & 0xFFFFFFF0u) << 32) | (u64)(((v1 & 15u) << 4) + kbase);
                u64 a2 = ((u64)(v2 & 0xFFFFFFF0u) << 32) | (u64)(((v2 & 15u) << 4) + kbase);
                #pragma unroll
                for (int m = 1; m <= 8; m <<= 1){
                    const u64 o1 = (u64)__shfl_xor((long long)a1, m, 16);
                    const u64 o2 = (u64)__shfl_xor((long long)a2, m, 16);
                    const u64 t  = a1 > o1 ? a1 : o1;
                    a1 = a1 < o1 ? a1 : o1;
                    const u64 u2 = a2 < o2 ? a2 : o2;
                    a2 = t < u2 ? t : u2;
                }
                if (col == 0){
                    const int row = rbl * 16 + ((ln >> 4) << 2) + rg;
                    mslot[row * 9 + wv * 2 + 0] = a1;
                    mslot[row * 9 + wv * 2 + 1] = a2;
                }
            }
        }
        __syncthreads();   // all wave top-2 written

        // ---- merge: top-4 per row from 4 waves x top-2 (u64 lexicographic) ----
        if (tid < BN){
            u64 c0 = ~0ull, c1 = ~0ull, c2m = ~0ull, c3 = ~0ull;
            #pragma unroll
            for (int i = 0; i < 8; ++i){
                const u64 v = mslot[tid * 9 + i];
                INS4_64(v, c0, c1, c2m, c3);
            }
            cand[tid][0] = (int)(c0 & 1023u);
            cand[tid][1] = (int)(c1 & 1023u);
            cand[tid][2] = (int)(c2m & 1023u);
            cand[tid][3] = (int)(c3 & 1023u);
        }
        __syncthreads();

        // ---- exact XLA-bits re-eval of 4 candidates (256 threads = 64 rows x 4) ----
        {
            const int row = tid >> 2, cd = tid & 3;
            const int k = cand[row][cd];
            const float* cw = cb + (size_t)k * W;
            float r2 = 0.f, dot = 0.f;
            for (int w = 0; w < W; ++w){
                const float rv = Rt[row][w];
                r2  = faddr(r2, fmulr(rv, rv));
                dot = __fmaf_rn(rv, cw[w], dot);
            }
            dve[row][cd] = faddr(fsubr(r2, faddr(dot, dot)), c2g[st * K + k]);
        }
        __syncthreads();

        // ---- decide: lexicographic (d2, k) min among 4 = XLA first-min ----
        if (tid < BN){
            float bd = dve[tid][0]; int bk = cand[tid][0];
            #pragma unroll
            for (int j = 1; j < 4; ++j){
                const float d = dve[tid][j]; const int k = cand[tid][j];
                if (d < bd || (d == bd && k < bk)){ bd = d; bk = k; }
            }
            widx[tid] = bk;
            out[(size_t)st * NRW + (n0 + tid)] = (float)bk;
            out[(size_t)C * NRW + (size_t)(n0 + tid) * C + st] = __fsqrt_rn(fmaxf(bd, 0.f));
        }
        __syncthreads();

        // ---- residual -= cb[idx], elementwise f32 (bit-exact) ----
        if (st < C - 1){
            for (int e = tid; e < BN * 32; e += NT){
                const int row = e >> 5, q = e & 31;
                const float4 v = cb4[(size_t)widx[row] * 32 + q];
                float* rp = &Rt[row][q * 4];
                rp[0] = fsubr(rp[0], v.x);
                rp[1] = fsubr(rp[1], v.y);
                rp[2] = fsubr(rp[2], v.z);
                rp[3] = fsubr(rp[3], v.w);
            }
        }
    }
}

extern "C" void kernel_launch(void* const* d_in, const int* in_sizes, int n_in,
                              void* d_out, int out_size, void* d_ws, size_t ws_size,
                              hipStream_t stream) {
    const float* X  = (const float*)d_in[0];
    const float* CB = (const float*)d_in[1];
    float* out = (float*)d_out;

    float* c2g = (float*)d_ws;                    // 16 KB
    f16*   Bh  = (f16*)((char*)d_ws + 16384);     // 1 MB

    c2_kernel<<<dim3((C * K + 255) / 256), 256, 0, stream>>>(CB, c2g);
    split_kernel<<<dim3(C * K * 16 / 256), 256, 0, stream>>>(CB, Bh);
    rq18_kernel<<<dim3(NRW / BN), NT, 0, stream>>>(X, CB, c2g, Bh, out);
}